// Round 1
// baseline (2619.258 us; speedup 1.0000x reference)
//
#include <hip/hip_runtime.h>

// Fused ConvTranspose3d(3->16, k3, s2, p1) * 0.5 -> AvgPool(2) -> +bias -> *1.0
// == VALID 2x2x2 conv, stride 1: x(4,3,128,128,128) -> out(4,16,127,127,127)
//
// out[n,oc,od,oh,ow] = fb[oc] + sum_{ic,a,b,c} F[oc,ic,a,b,c] * x[n,ic,od+a,oh+b,ow+c]
//   F[oc,ic,a,b,c] = 0.0625 * sum_{kd in S(a), kh in S(b), kw in S(c)} W[ic,oc,kd,kh,kw]
//   S(0) = {1,2}, S(1) = {0}
//   fb[oc] = conv_bias[oc]*0.5 + ext_bias[oc]

#define NB 4
#define IC 3
#define OC 16
#define XS 128      // input spatial
#define OS 127      // output spatial

__device__ __forceinline__ float4 fma4(const float4 a, const float s, float4 c) {
    c.x = __builtin_fmaf(a.x, s, c.x);
    c.y = __builtin_fmaf(a.y, s, c.y);
    c.z = __builtin_fmaf(a.z, s, c.z);
    c.w = __builtin_fmaf(a.w, s, c.w);
    return c;
}

__global__ __launch_bounds__(256, 4)
void fused_convt_pool_kernel(const float* __restrict__ X,
                             const float* __restrict__ W,   // (ic, oc, 3,3,3)
                             const float* __restrict__ CB,  // (16,)
                             const float* __restrict__ EB,  // (16,)
                             float* __restrict__ OUT) {
    // fwS layout: [(ic*16 + oc)*8 + (a*4 + b*2 + c)] -> two float4 per (ic,oc)
    __shared__ float fwS[IC * OC * 8];
    __shared__ float fbS[OC];

    for (int t = threadIdx.x; t < IC * OC * 8; t += 256) {
        int ic  = t >> 7;          // /128
        int oc  = (t >> 3) & 15;
        int abc = t & 7;
        int a = (abc >> 2) & 1, b = (abc >> 1) & 1, c = abc & 1;
        int kdlo = a ? 0 : 1, kdhi = a ? 0 : 2;
        int khlo = b ? 0 : 1, khhi = b ? 0 : 2;
        int kwlo = c ? 0 : 1, kwhi = c ? 0 : 2;
        const float* wp = W + (ic * OC + oc) * 27;
        float s = 0.f;
        for (int kd = kdlo; kd <= kdhi; ++kd)
            for (int kh = khlo; kh <= khhi; ++kh)
                for (int kw = kwlo; kw <= kwhi; ++kw)
                    s += wp[kd * 9 + kh * 3 + kw];
        fwS[t] = s * 0.0625f;
    }
    if (threadIdx.x < OC)
        fbS[threadIdx.x] = CB[threadIdx.x] * 0.5f + EB[threadIdx.x];
    __syncthreads();

    // Each thread: one (n, od, oh), 4 ow positions strided by 32, all 16 oc.
    int gtid = blockIdx.x * 256 + threadIdx.x;
    const int total = NB * OS * OS * 32;   // 2,064,512
    if (gtid >= total) return;

    int ow0  = gtid & 31;
    int rest = gtid >> 5;
    int oh = rest % OS; rest /= OS;
    int od = rest % OS;
    int n  = rest / OS;

    int owk[4], ow1[4];
#pragma unroll
    for (int k = 0; k < 4; ++k) {
        owk[k] = ow0 + 32 * k;
        int w1 = owk[k] + 1;
        ow1[k] = (w1 > OS) ? OS : w1;   // clamp 128 -> 127 (value unused; avoids OOB)
    }

    float4 acc[OC];
#pragma unroll
    for (int oc = 0; oc < OC; ++oc) {
        float b = fbS[oc];
        acc[oc] = make_float4(b, b, b, b);
    }

#pragma unroll
    for (int ic = 0; ic < IC; ++ic) {
        const float* xb = X + ((((size_t)n * IC + ic) * XS + od) * XS + oh) * XS;
        float4 xv[2][2][2];   // [a][b][c], packed over k
#pragma unroll
        for (int a = 0; a < 2; ++a) {
#pragma unroll
            for (int b = 0; b < 2; ++b) {
                const float* r = xb + a * (XS * XS) + b * XS;
                xv[a][b][0] = make_float4(r[owk[0]], r[owk[1]], r[owk[2]], r[owk[3]]);
                xv[a][b][1] = make_float4(r[ow1[0]], r[ow1[1]], r[ow1[2]], r[ow1[3]]);
            }
        }
        const float4* wq = (const float4*)&fwS[ic * OC * 8];
#pragma unroll
        for (int oc = 0; oc < OC; ++oc) {
            float4 w0 = wq[oc * 2 + 0];   // (a,b,c) = 000,001,010,011
            float4 w1 = wq[oc * 2 + 1];   // (a,b,c) = 100,101,110,111
            acc[oc] = fma4(xv[0][0][0], w0.x, acc[oc]);
            acc[oc] = fma4(xv[0][0][1], w0.y, acc[oc]);
            acc[oc] = fma4(xv[0][1][0], w0.z, acc[oc]);
            acc[oc] = fma4(xv[0][1][1], w0.w, acc[oc]);
            acc[oc] = fma4(xv[1][0][0], w1.x, acc[oc]);
            acc[oc] = fma4(xv[1][0][1], w1.y, acc[oc]);
            acc[oc] = fma4(xv[1][1][0], w1.z, acc[oc]);
            acc[oc] = fma4(xv[1][1][1], w1.w, acc[oc]);
        }
    }

    const size_t ocStride = (size_t)OS * OS * OS;        // 2,048,383
    size_t obase = (size_t)n * OC * ocStride + ((size_t)od * OS + oh) * OS;
#pragma unroll
    for (int oc = 0; oc < OC; ++oc) {
        float* o = OUT + obase + (size_t)oc * ocStride;
        o[owk[0]] = acc[oc].x;
        o[owk[1]] = acc[oc].y;
        o[owk[2]] = acc[oc].z;
        if (owk[3] < OS) o[owk[3]] = acc[oc].w;
    }
}

extern "C" void kernel_launch(void* const* d_in, const int* in_sizes, int n_in,
                              void* d_out, int out_size, void* d_ws, size_t ws_size,
                              hipStream_t stream) {
    const float* X  = (const float*)d_in[0];   // (4,3,128,128,128)
    const float* W  = (const float*)d_in[1];   // (3,16,3,3,3)
    const float* CB = (const float*)d_in[2];   // (16,)
    const float* EB = (const float*)d_in[3];   // (16,1,1,1) flat 16
    float* OUT = (float*)d_out;                // (4,16,127,127,127)

    const int total = NB * OS * OS * 32;
    const int blocks = (total + 255) / 256;
    fused_convt_pool_kernel<<<blocks, 256, 0, stream>>>(X, W, CB, EB, OUT);
}

// Round 2
// 722.607 us; speedup vs baseline: 3.6247x; 3.6247x over previous
//
#include <hip/hip_runtime.h>

// Fused ConvTranspose3d(3->16, k3, s2, p1) * 0.5 -> AvgPool(2) -> +bias
// == VALID 2x2x2 conv, stride 1: x(4,3,128,128,128) -> out(4,16,127,127,127)
//
// R2: R1 spilled (VGPR_Count=64 but ~120 live regs needed -> 7.3 GB of
// scratch traffic). This version keeps ~75 live VGPRs:
//   - 8 oc per thread (oc-half is a grid dim), acc = 32 VGPRs
//   - folded weights/bias precomputed into d_ws by a prep kernel; main
//     kernel reads them at block-uniform addresses -> SGPRs via s_load
//   - 4 consecutive ow per thread -> aligned global_load_dwordx4 for x
//   - XCD-contiguous block swizzle for L2 locality of the x re-reads

#define NB 4
#define IC 3
#define OC 16
#define XS 128              // input spatial
#define OS 127              // output spatial
#define OS3 (127 * 127 * 127)
#define OHB 16              // oh blocks of 8 rows (16*8=128, last row masked)
#define NBLK (NB * OS * OHB * 2)   // 4*127*16*2 = 16256

// ---- prep: fold 3x3x3 weight -> fw[3][16][8] (tap = a*4+b*2+c), bias fb[16]
__global__ void prep_kernel(const float* __restrict__ W,   // (ic, oc, 3,3,3)
                            const float* __restrict__ CB,  // (16,)
                            const float* __restrict__ EB,  // (16,)
                            float* __restrict__ ws) {
    int t = threadIdx.x;
    if (t < IC * OC * 8) {
        int ic  = t >> 7;
        int oc  = (t >> 3) & 15;
        int abc = t & 7;
        int a = (abc >> 2) & 1, b = (abc >> 1) & 1, c = abc & 1;
        int kdlo = a ? 0 : 1, kdhi = a ? 0 : 2;
        int khlo = b ? 0 : 1, khhi = b ? 0 : 2;
        int kwlo = c ? 0 : 1, kwhi = c ? 0 : 2;
        const float* wp = W + (ic * OC + oc) * 27;
        float s = 0.f;
        for (int kd = kdlo; kd <= kdhi; ++kd)
            for (int kh = khlo; kh <= khhi; ++kh)
                for (int kw = kwlo; kw <= kwhi; ++kw)
                    s += wp[kd * 9 + kh * 3 + kw];
        ws[t] = s * 0.0625f;
    }
    if (t < OC) ws[IC * OC * 8 + t] = CB[t] * 0.5f + EB[t];
}

// c=0 tap: acc += q * s
__device__ __forceinline__ float4 fc0(const float4 q, const float s, float4 a) {
    a.x = __builtin_fmaf(q.x, s, a.x);
    a.y = __builtin_fmaf(q.y, s, a.y);
    a.z = __builtin_fmaf(q.z, s, a.z);
    a.w = __builtin_fmaf(q.w, s, a.w);
    return a;
}
// c=1 tap: acc += shift(q, e) * s   (shifted window: q.y q.z q.w e)
__device__ __forceinline__ float4 fc1(const float4 q, const float e,
                                      const float s, float4 a) {
    a.x = __builtin_fmaf(q.y, s, a.x);
    a.y = __builtin_fmaf(q.z, s, a.y);
    a.z = __builtin_fmaf(q.w, s, a.z);
    a.w = __builtin_fmaf(e,   s, a.w);
    return a;
}

__global__ __launch_bounds__(256, 2)
void conv_main(const float* __restrict__ X,
               const float* __restrict__ FW,   // ws: fw[384] then fb[16]
               float* __restrict__ OUT) {
    // XCD-contiguous swizzle: XCD k (= blockIdx%8) gets one contiguous chunk
    int B    = blockIdx.x;
    int work = (B & 7) * (NBLK / 8) + (B >> 3);
    int och  = work & 1;            // oc half (innermost: both halves reuse x)
    int w2   = work >> 1;
    int ohb  = w2 & 15;             // next-fastest: oh block of 8 rows
    int w3   = w2 >> 4;             // 0 .. 4*127
    int od   = w3 % OS;
    int n    = w3 / OS;

    int t   = threadIdx.x;
    int ohl = t >> 5;               // 0..7
    int g   = t & 31;               // ow group
    int ow0 = g << 2;               // 4 consecutive ow
    int oh  = (ohb << 3) + ohl;     // 0..127
    bool valid = (oh < OS);
    int ohc = valid ? oh : (OS - 1);            // clamp loads for masked row
    int e_off = (ow0 + 4 < XS) ? (ow0 + 4) : (XS - 1);  // clamp tail load

    const float* fw = FW;                        // block-uniform -> s_load
    const float* fb = FW + IC * OC * 8;

    float4 acc[8];
#pragma unroll
    for (int oc = 0; oc < 8; ++oc) {
        float bv = fb[och * 8 + oc];
        acc[oc] = make_float4(bv, bv, bv, bv);
    }

#pragma unroll
    for (int ic = 0; ic < IC; ++ic) {
        const float* xb = X + (((size_t)(n * IC + ic) * XS + od) * XS + ohc) * XS;
        float4 q[2][2];
        float  e[2][2];
#pragma unroll
        for (int a = 0; a < 2; ++a)
#pragma unroll
            for (int b = 0; b < 2; ++b) {
                const float* r = xb + (a * XS + b) * XS;
                q[a][b] = *(const float4*)(r + ow0);   // 16B aligned
                e[a][b] = r[e_off];
            }
        const float* wi = fw + (ic * OC + och * 8) * 8;
#pragma unroll
        for (int oc = 0; oc < 8; ++oc) {
            const float* w = wi + oc * 8;              // uniform -> SGPRs
            float4 a4 = acc[oc];
            a4 = fc0(q[0][0],          w[0], a4);
            a4 = fc1(q[0][0], e[0][0], w[1], a4);
            a4 = fc0(q[0][1],          w[2], a4);
            a4 = fc1(q[0][1], e[0][1], w[3], a4);
            a4 = fc0(q[1][0],          w[4], a4);
            a4 = fc1(q[1][0], e[1][0], w[5], a4);
            a4 = fc0(q[1][1],          w[6], a4);
            a4 = fc1(q[1][1], e[1][1], w[7], a4);
            acc[oc] = a4;
        }
    }

    if (valid) {
        size_t obase = (size_t)(n * OC + och * 8) * OS3
                     + ((size_t)od * OS + oh) * OS + ow0;
#pragma unroll
        for (int oc = 0; oc < 8; ++oc) {
            float* o = OUT + obase + (size_t)oc * OS3;
            o[0] = acc[oc].x;
            o[1] = acc[oc].y;
            o[2] = acc[oc].z;
            if (g < 31) o[3] = acc[oc].w;   // ow=127 masked
        }
    }
}

extern "C" void kernel_launch(void* const* d_in, const int* in_sizes, int n_in,
                              void* d_out, int out_size, void* d_ws, size_t ws_size,
                              hipStream_t stream) {
    const float* X  = (const float*)d_in[0];   // (4,3,128,128,128)
    const float* W  = (const float*)d_in[1];   // (3,16,3,3,3)
    const float* CB = (const float*)d_in[2];   // (16,)
    const float* EB = (const float*)d_in[3];   // (16,1,1,1) flat 16
    float* OUT = (float*)d_out;                // (4,16,127,127,127)
    float* ws  = (float*)d_ws;                 // 384 fw + 16 fb = 1600 B

    prep_kernel<<<1, 384, 0, stream>>>(W, CB, EB, ws);
    conv_main<<<NBLK, 256, 0, stream>>>(X, ws, OUT);
}